// Round 1
// baseline (433.967 us; speedup 1.0000x reference)
//
#include <hip/hip_runtime.h>

#define DEV __device__ __forceinline__

typedef __attribute__((ext_vector_type(8))) short short8;
typedef __attribute__((ext_vector_type(4))) float floatx4;

DEV unsigned short f2bs(float x) {
    unsigned u = __float_as_uint(x);
    unsigned r = (u + 0x7fffu + ((u >> 16) & 1u)) >> 16;
    return (unsigned short)r;
}
DEV float b2f(unsigned short u) { return __uint_as_float(((unsigned)u) << 16); }

// ---------------- GroupNorm stats: one block per (b,g), 16ch*4096px contiguous ----------------
__global__ void gn_stats_kernel(const float* __restrict__ x, float* __restrict__ stats) {
    int bg = blockIdx.x;  // 0..127
    const float4* p = (const float4*)(x + (size_t)bg * 65536);
    int tid = threadIdx.x;
    float s = 0.f, ss = 0.f;
    for (int i = tid; i < 16384; i += 256) {
        float4 v = p[i];
        s += v.x + v.y + v.z + v.w;
        ss += v.x * v.x + v.y * v.y + v.z * v.z + v.w * v.w;
    }
    for (int off = 32; off; off >>= 1) { s += __shfl_down(s, off); ss += __shfl_down(ss, off); }
    __shared__ float rs[4], rss[4];
    int wave = tid >> 6, lane = tid & 63;
    if (lane == 0) { rs[wave] = s; rss[wave] = ss; }
    __syncthreads();
    if (tid == 0) {
        float S = rs[0] + rs[1] + rs[2] + rs[3];
        float SS = rss[0] + rss[1] + rss[2] + rss[3];
        float mean = S * (1.f / 65536.f);
        float var = SS * (1.f / 65536.f) - mean * mean;
        stats[bg * 2] = mean;
        stats[bg * 2 + 1] = rsqrtf(var + 1e-5f);
    }
}

// ------------- GN apply + transpose: x[b][c][p] fp32 -> h_t[b][p][c] bf16 (64x64 tiles) -------------
__global__ void gn_apply_kernel(const float* __restrict__ x, const float* __restrict__ stats,
                                const float* __restrict__ gw, const float* __restrict__ gb,
                                unsigned short* __restrict__ ht) {
    __shared__ __align__(16) unsigned short t[64][72];
    int b = blockIdx.z, c0 = blockIdx.y * 64, p0 = blockIdx.x * 64;
    int tid = threadIdx.x;
    const float* xb = x + ((size_t)b * 512 + c0) * 4096 + p0;
#pragma unroll
    for (int pass = 0; pass < 4; ++pass) {
        int cl = pass * 16 + (tid >> 4);
        int pq = (tid & 15) * 4;
        float4 v = *(const float4*)(xb + (size_t)cl * 4096 + pq);
        int c = c0 + cl, g = c >> 4;
        float mean = stats[(b * 32 + g) * 2], rstd = stats[(b * 32 + g) * 2 + 1];
        float sw = gw[c] * rstd;
        float sb = gb[c] - mean * sw;
        t[pq + 0][cl] = f2bs(v.x * sw + sb);
        t[pq + 1][cl] = f2bs(v.y * sw + sb);
        t[pq + 2][cl] = f2bs(v.z * sw + sb);
        t[pq + 3][cl] = f2bs(v.w * sw + sb);
    }
    __syncthreads();
    unsigned short* hb = ht + ((size_t)b * 4096 + p0) * 512 + c0;
#pragma unroll
    for (int pass = 0; pass < 2; ++pass) {
        int pl = pass * 32 + (tid >> 3);
        int c8 = (tid & 7) * 8;
        *(uint4*)(hb + (size_t)pl * 512 + c8) = *(const uint4*)&t[pl][c8];
    }
}

// ---------------- fp32 -> bf16 weight convert ----------------
__global__ void cvt_bf16_kernel(const float* __restrict__ s, unsigned short* __restrict__ d, int n4) {
    int i = blockIdx.x * 256 + threadIdx.x;
    if (i >= n4) return;
    float4 v = ((const float4*)s)[i];
    ushort4 o;
    o.x = f2bs(v.x); o.y = f2bs(v.y); o.z = f2bs(v.z); o.w = f2bs(v.w);
    ((ushort4*)d)[i] = o;
}

// ---------------- in-place row softmax over bf16 scores, 1 block = 1 row of 4096 ----------------
__global__ void softmax_kernel(unsigned short* __restrict__ sc) {
    size_t row = blockIdx.x;
    unsigned short* p = sc + row * 4096;
    int tid = threadIdx.x, wave = tid >> 6, lane = tid & 63;
    uint4 u0 = ((const uint4*)p)[tid * 2];
    uint4 u1 = ((const uint4*)p)[tid * 2 + 1];
    float f[16];
    const unsigned short* a = (const unsigned short*)&u0;
    const unsigned short* b = (const unsigned short*)&u1;
#pragma unroll
    for (int i = 0; i < 8; i++) { f[i] = b2f(a[i]); f[8 + i] = b2f(b[i]); }
    float mx = -1e30f;
#pragma unroll
    for (int i = 0; i < 16; i++) mx = fmaxf(mx, f[i]);
    for (int off = 32; off; off >>= 1) mx = fmaxf(mx, __shfl_xor(mx, off));
    __shared__ float red[8];
    if (lane == 0) red[wave] = mx;
    __syncthreads();
    mx = fmaxf(fmaxf(red[0], red[1]), fmaxf(red[2], red[3]));
    float s = 0.f;
#pragma unroll
    for (int i = 0; i < 16; i++) { f[i] = __expf(f[i] - mx); s += f[i]; }
    for (int off = 32; off; off >>= 1) s += __shfl_xor(s, off);
    if (lane == 0) red[4 + wave] = s;
    __syncthreads();
    s = red[4] + red[5] + red[6] + red[7];
    float inv = 1.f / s;
    __align__(16) unsigned short o[16];
#pragma unroll
    for (int i = 0; i < 16; i++) o[i] = f2bs(f[i] * inv);
    ((uint4*)p)[tid * 2] = *(const uint4*)&o[0];
    ((uint4*)p)[tid * 2 + 1] = *(const uint4*)&o[8];
}

// ---------------- NT GEMM: C[m][n] = sum_k A[m][k]*B[n][k], bf16 in, fp32 acc ----------------
// EPI: 0 = bf16 out + bias[n]; 1 = bf16 out + bias[m]; 2 = bf16 out, * scale;
//      3 = bf16 out; 4 = f32 out + bias[m] + residual
template <int EPI>
__global__ void gemm_nt(const unsigned short* __restrict__ A, long long sAb,
                        const unsigned short* __restrict__ B, long long sBb,
                        void* __restrict__ Cv, long long sCb,
                        const float* __restrict__ bias,
                        const float* __restrict__ resid, long long sRb,
                        int M, int N, int K, float scale) {
    __shared__ __align__(16) unsigned short lA[128 * 64];
    __shared__ __align__(16) unsigned short lB[128 * 64];
    const int tid = threadIdx.x;
    const int wave = tid >> 6, lane = tid & 63;
    const int m0 = blockIdx.y * 128, n0 = blockIdx.x * 128;
    const int bz = blockIdx.z;
    const unsigned short* Ab = A + (size_t)bz * sAb;
    const unsigned short* Bb = B + (size_t)bz * sBb;

    floatx4 acc[4][4];
#pragma unroll
    for (int i = 0; i < 4; i++)
#pragma unroll
        for (int j = 0; j < 4; j++) acc[i][j] = (floatx4){0.f, 0.f, 0.f, 0.f};

    const int wm = (wave >> 1) * 64, wn = (wave & 1) * 64;
    const int quad = lane >> 4;   // 0..3
    const int lc = lane & 15;     // 0..15

    const int nk = K >> 6;
    for (int kt = 0; kt < nk; ++kt) {
        const int kbase = kt * 64;
#pragma unroll
        for (int c = 0; c < 4; ++c) {
            int f = (c * 256 + tid) * 8;
            int r = f >> 6, cc = f & 63;
            const unsigned short* ga = Ab + (size_t)(m0 + r) * K + kbase + cc;
            const unsigned short* gb = Bb + (size_t)(n0 + r) * K + kbase + cc;
            __builtin_amdgcn_global_load_lds(
                (const __attribute__((address_space(1))) void*)ga,
                (__attribute__((address_space(3))) void*)&lA[(size_t)(c * 256 + wave * 64) * 8], 16, 0, 0);
            __builtin_amdgcn_global_load_lds(
                (const __attribute__((address_space(1))) void*)gb,
                (__attribute__((address_space(3))) void*)&lB[(size_t)(c * 256 + wave * 64) * 8], 16, 0, 0);
        }
        __syncthreads();
#pragma unroll
        for (int kk = 0; kk < 2; ++kk) {
            short8 af[4], bf[4];
#pragma unroll
            for (int i = 0; i < 4; i++)
                af[i] = *(const short8*)&lA[(size_t)(wm + i * 16 + lc) * 64 + kk * 32 + quad * 8];
#pragma unroll
            for (int j = 0; j < 4; j++)
                bf[j] = *(const short8*)&lB[(size_t)(wn + j * 16 + lc) * 64 + kk * 32 + quad * 8];
#pragma unroll
            for (int i = 0; i < 4; i++)
#pragma unroll
                for (int j = 0; j < 4; j++)
                    acc[i][j] = __builtin_amdgcn_mfma_f32_16x16x32_bf16(af[i], bf[j], acc[i][j], 0, 0, 0);
        }
        __syncthreads();
    }

    // epilogue: D row = quad*4 + reg, col = lane&15
    const int rowb = quad * 4;
#pragma unroll
    for (int i = 0; i < 4; i++) {
#pragma unroll
        for (int j = 0; j < 4; j++) {
#pragma unroll
            for (int r = 0; r < 4; r++) {
                int m = m0 + wm + i * 16 + rowb + r;
                int n = n0 + wn + j * 16 + lc;
                float v = acc[i][j][r];
                if constexpr (EPI == 2) v *= scale;
                if constexpr (EPI == 0) v += bias[n];
                if constexpr (EPI == 1 || EPI == 4) v += bias[m];
                size_t idx = (size_t)bz * sCb + (size_t)m * N + n;
                if constexpr (EPI == 4) {
                    v += resid[(size_t)bz * sRb + (size_t)m * N + n];
                    ((float*)Cv)[idx] = v;
                } else {
                    ((unsigned short*)Cv)[idx] = f2bs(v);
                }
            }
        }
    }
}

extern "C" void kernel_launch(void* const* d_in, const int* in_sizes, int n_in,
                              void* d_out, int out_size, void* d_ws, size_t ws_size,
                              hipStream_t stream) {
    (void)in_sizes; (void)n_in; (void)out_size; (void)ws_size;
    const float* x   = (const float*)d_in[0];
    const float* gnw = (const float*)d_in[1];
    const float* gnb = (const float*)d_in[2];
    const float* qw  = (const float*)d_in[3];
    const float* qb  = (const float*)d_in[4];
    const float* kw  = (const float*)d_in[5];
    const float* kb  = (const float*)d_in[6];
    const float* vw  = (const float*)d_in[7];
    const float* vb  = (const float*)d_in[8];
    const float* pw  = (const float*)d_in[9];
    const float* pb  = (const float*)d_in[10];
    float* out = (float*)d_out;

    char* ws = (char*)d_ws;
    // layout (bytes): h_t 0..16M (reused as O_t), q_t 16M, k_t 32M, v 48M,
    // weights 64M..66M, stats 66M, scores 67M..195M
    unsigned short* h_t = (unsigned short*)(ws);
    unsigned short* o_t = h_t;  // alias: h_t dead after v GEMM, O_t written after softmax
    unsigned short* q_t = (unsigned short*)(ws + (16ull << 20));
    unsigned short* k_t = (unsigned short*)(ws + (32ull << 20));
    unsigned short* vv  = (unsigned short*)(ws + (48ull << 20));
    unsigned short* wqb = (unsigned short*)(ws + (64ull << 20));
    unsigned short* wkb = wqb + 262144;
    unsigned short* wvb = wqb + 2 * 262144;
    unsigned short* wpb = wqb + 3 * 262144;
    float* stats = (float*)(ws + (66ull << 20));
    unsigned short* sc = (unsigned short*)(ws + (67ull << 20));

    const long long sP = 2097152;   // 4096*512 elements per batch
    const long long sS = 16777216;  // 4096*4096 elements per batch

    cvt_bf16_kernel<<<256, 256, 0, stream>>>(qw, wqb, 65536);
    cvt_bf16_kernel<<<256, 256, 0, stream>>>(kw, wkb, 65536);
    cvt_bf16_kernel<<<256, 256, 0, stream>>>(vw, wvb, 65536);
    cvt_bf16_kernel<<<256, 256, 0, stream>>>(pw, wpb, 65536);
    gn_stats_kernel<<<128, 256, 0, stream>>>(x, stats);
    gn_apply_kernel<<<dim3(64, 8, 4), 256, 0, stream>>>(x, stats, gnw, gnb, h_t);
    // q_t[p][o], k_t[p][o]: M=4096(p), N=512(o), K=512(c); A=h_t, B=weight
    gemm_nt<0><<<dim3(4, 32, 4), 256, 0, stream>>>(h_t, sP, wqb, 0, q_t, sP, qb, nullptr, 0, 4096, 512, 512, 1.f);
    gemm_nt<0><<<dim3(4, 32, 4), 256, 0, stream>>>(h_t, sP, wkb, 0, k_t, sP, kb, nullptr, 0, 4096, 512, 512, 1.f);
    // v[d][p]: M=512(d), N=4096(p), K=512(c); A=vw, B=h_t
    gemm_nt<1><<<dim3(32, 4, 4), 256, 0, stream>>>(wvb, 0, h_t, sP, vv, sP, vb, nullptr, 0, 512, 4096, 512, 1.f);
    // S[q][k] = q_t . k_t^T * C^-0.5 : M=N=4096, K=512
    gemm_nt<2><<<dim3(32, 32, 4), 256, 0, stream>>>(q_t, sP, k_t, sP, sc, sS, nullptr, nullptr, 0,
                                                    4096, 4096, 512, 0.044194173824159216f);
    softmax_kernel<<<16384, 256, 0, stream>>>(sc);
    // O_t[q][d]: M=4096(q), N=512(d), K=4096(k); A=attn, B=v
    gemm_nt<3><<<dim3(4, 32, 4), 256, 0, stream>>>(sc, sS, vv, sP, o_t, sP, nullptr, nullptr, 0, 4096, 512, 4096, 1.f);
    // y[o][p] = x + pw . O_t^T + pb : M=512(o), N=4096(p), K=512(d)
    gemm_nt<4><<<dim3(32, 4, 4), 256, 0, stream>>>(wpb, 0, o_t, sP, (void*)out, sP, pb, x, sP, 512, 4096, 512, 1.f);
}

// Round 2
// 413.246 us; speedup vs baseline: 1.0501x; 1.0501x over previous
//
#include <hip/hip_runtime.h>

#define DEV __device__ __forceinline__

typedef __attribute__((ext_vector_type(8))) short short8;
typedef __attribute__((ext_vector_type(4))) float floatx4;

DEV unsigned short f2bs(float x) {
    unsigned u = __float_as_uint(x);
    unsigned r = (u + 0x7fffu + ((u >> 16) & 1u)) >> 16;
    return (unsigned short)r;
}

// ---------------- GroupNorm stats: one block per (b,g), 16ch*4096px contiguous ----------------
// also zeroes rowsum[16384] (128 blocks x 128 floats)
__global__ void gn_stats_kernel(const float* __restrict__ x, float* __restrict__ stats,
                                float* __restrict__ rowsum) {
    int bg = blockIdx.x;  // 0..127
    int tid = threadIdx.x;
    if (tid < 128) rowsum[bg * 128 + tid] = 0.f;
    const float4* p = (const float4*)(x + (size_t)bg * 65536);
    float s = 0.f, ss = 0.f;
    for (int i = tid; i < 16384; i += 256) {
        float4 v = p[i];
        s += v.x + v.y + v.z + v.w;
        ss += v.x * v.x + v.y * v.y + v.z * v.z + v.w * v.w;
    }
    for (int off = 32; off; off >>= 1) { s += __shfl_down(s, off); ss += __shfl_down(ss, off); }
    __shared__ float rs[4], rss[4];
    int wave = tid >> 6, lane = tid & 63;
    if (lane == 0) { rs[wave] = s; rss[wave] = ss; }
    __syncthreads();
    if (tid == 0) {
        float S = rs[0] + rs[1] + rs[2] + rs[3];
        float SS = rss[0] + rss[1] + rss[2] + rss[3];
        float mean = S * (1.f / 65536.f);
        float var = SS * (1.f / 65536.f) - mean * mean;
        stats[bg * 2] = mean;
        stats[bg * 2 + 1] = rsqrtf(var + 1e-5f);
    }
}

// ------------- GN apply + transpose: x[b][c][p] fp32 -> h_t[b][p][c] bf16 (64x64 tiles) -------------
__global__ void gn_apply_kernel(const float* __restrict__ x, const float* __restrict__ stats,
                                const float* __restrict__ gw, const float* __restrict__ gb,
                                unsigned short* __restrict__ ht) {
    __shared__ __align__(16) unsigned short t[64][72];
    int b = blockIdx.z, c0 = blockIdx.y * 64, p0 = blockIdx.x * 64;
    int tid = threadIdx.x;
    const float* xb = x + ((size_t)b * 512 + c0) * 4096 + p0;
#pragma unroll
    for (int pass = 0; pass < 4; ++pass) {
        int cl = pass * 16 + (tid >> 4);
        int pq = (tid & 15) * 4;
        float4 v = *(const float4*)(xb + (size_t)cl * 4096 + pq);
        int c = c0 + cl, g = c >> 4;
        float mean = stats[(b * 32 + g) * 2], rstd = stats[(b * 32 + g) * 2 + 1];
        float sw = gw[c] * rstd;
        float sb = gb[c] - mean * sw;
        t[pq + 0][cl] = f2bs(v.x * sw + sb);
        t[pq + 1][cl] = f2bs(v.y * sw + sb);
        t[pq + 2][cl] = f2bs(v.z * sw + sb);
        t[pq + 3][cl] = f2bs(v.w * sw + sb);
    }
    __syncthreads();
    unsigned short* hb = ht + ((size_t)b * 4096 + p0) * 512 + c0;
#pragma unroll
    for (int pass = 0; pass < 2; ++pass) {
        int pl = pass * 32 + (tid >> 3);
        int c8 = (tid & 7) * 8;
        *(uint4*)(hb + (size_t)pl * 512 + c8) = *(const uint4*)&t[pl][c8];
    }
}

// ---------------- fp32 -> bf16 weight convert ----------------
__global__ void cvt_bf16_kernel(const float* __restrict__ s, unsigned short* __restrict__ d, int n4) {
    int i = blockIdx.x * 256 + threadIdx.x;
    if (i >= n4) return;
    float4 v = ((const float4*)s)[i];
    ushort4 o;
    o.x = f2bs(v.x); o.y = f2bs(v.y); o.z = f2bs(v.z); o.w = f2bs(v.w);
    ((ushort4*)d)[i] = o;
}

// ---------------- NT GEMM: C[m][n] = sum_k A[m][k]*B[n][k], bf16 in, fp32 acc ----------------
// EPI: 0 = bf16 out + bias[n]
//      1 = bf16 out + bias[m]
//      2 = bf16 out = exp(v*scale), atomicAdd per-row sums into rowsum[bz*M+m]
//      3 = bf16 out = v / bias[bz*M+m]   (row-normalize by precomputed sum)
//      4 = f32 out + bias[m] + residual
// SWZ: XCD-aware flat-grid decode for M=4096,N=512,B=4 (O-GEMM only)
template <int EPI, bool SWZ>
__global__ void gemm_nt(const unsigned short* __restrict__ A, long long sAb,
                        const unsigned short* __restrict__ B, long long sBb,
                        void* __restrict__ Cv, long long sCb,
                        const float* __restrict__ bias,
                        const float* __restrict__ resid, long long sRb,
                        float* __restrict__ rowsum,
                        int M, int N, int K, float scale) {
    __shared__ __align__(16) unsigned short lA[128 * 64];
    __shared__ __align__(16) unsigned short lB[128 * 64];
    const int tid = threadIdx.x;
    const int wave = tid >> 6, lane = tid & 63;
    int m0, n0, bz;
    if constexpr (SWZ) {
        // 512 blocks: xcd = flat&7 owns 16 contiguous (b,m)-stripes x 4 n-tiles.
        int flat = blockIdx.x;
        int xcd = flat & 7, idx = flat >> 3;
        int nt = idx & 3, si = idx >> 2;           // nt 0..3, si 0..15
        int stripe = xcd * 16 + si;                // 0..127 = (b,mtile)
        m0 = (stripe & 31) * 128;
        n0 = nt * 128;
        bz = stripe >> 5;
    } else {
        m0 = blockIdx.y * 128; n0 = blockIdx.x * 128; bz = blockIdx.z;
    }
    const unsigned short* Ab = A + (size_t)bz * sAb;
    const unsigned short* Bb = B + (size_t)bz * sBb;

    floatx4 acc[4][4];
#pragma unroll
    for (int i = 0; i < 4; i++)
#pragma unroll
        for (int j = 0; j < 4; j++) acc[i][j] = (floatx4){0.f, 0.f, 0.f, 0.f};

    const int wm = (wave >> 1) * 64, wn = (wave & 1) * 64;
    const int quad = lane >> 4;   // 0..3
    const int lc = lane & 15;     // 0..15

    const int nk = K >> 6;
    for (int kt = 0; kt < nk; ++kt) {
        const int kbase = kt * 64;
#pragma unroll
        for (int c = 0; c < 4; ++c) {
            int f = (c * 256 + tid) * 8;
            int r = f >> 6, cc = f & 63;
            const unsigned short* ga = Ab + (size_t)(m0 + r) * K + kbase + cc;
            const unsigned short* gb = Bb + (size_t)(n0 + r) * K + kbase + cc;
            __builtin_amdgcn_global_load_lds(
                (const __attribute__((address_space(1))) void*)ga,
                (__attribute__((address_space(3))) void*)&lA[(size_t)(c * 256 + wave * 64) * 8], 16, 0, 0);
            __builtin_amdgcn_global_load_lds(
                (const __attribute__((address_space(1))) void*)gb,
                (__attribute__((address_space(3))) void*)&lB[(size_t)(c * 256 + wave * 64) * 8], 16, 0, 0);
        }
        __syncthreads();
#pragma unroll
        for (int kk = 0; kk < 2; ++kk) {
            short8 af[4], bf[4];
#pragma unroll
            for (int i = 0; i < 4; i++)
                af[i] = *(const short8*)&lA[(size_t)(wm + i * 16 + lc) * 64 + kk * 32 + quad * 8];
#pragma unroll
            for (int j = 0; j < 4; j++)
                bf[j] = *(const short8*)&lB[(size_t)(wn + j * 16 + lc) * 64 + kk * 32 + quad * 8];
#pragma unroll
            for (int i = 0; i < 4; i++)
#pragma unroll
                for (int j = 0; j < 4; j++)
                    acc[i][j] = __builtin_amdgcn_mfma_f32_16x16x32_bf16(af[i], bf[j], acc[i][j], 0, 0, 0);
        }
        __syncthreads();
    }

    // epilogue: D row = quad*4 + reg, col = lane&15
    const int rowb = quad * 4;
#pragma unroll
    for (int i = 0; i < 4; i++) {
#pragma unroll
        for (int r = 0; r < 4; r++) {
            const int m = m0 + wm + i * 16 + rowb + r;
            float pscale = 1.f;
            if constexpr (EPI == 3) pscale = 1.f / bias[(size_t)bz * M + m];
            float rsacc = 0.f;
#pragma unroll
            for (int j = 0; j < 4; j++) {
                const int n = n0 + wn + j * 16 + lc;
                float v = acc[i][j][r];
                size_t idx = (size_t)bz * sCb + (size_t)m * N + n;
                if constexpr (EPI == 0) {
                    ((unsigned short*)Cv)[idx] = f2bs(v + bias[n]);
                } else if constexpr (EPI == 1) {
                    ((unsigned short*)Cv)[idx] = f2bs(v + bias[m]);
                } else if constexpr (EPI == 2) {
                    float e = __expf(v * scale);
                    ((unsigned short*)Cv)[idx] = f2bs(e);
                    rsacc += e;
                } else if constexpr (EPI == 3) {
                    ((unsigned short*)Cv)[idx] = f2bs(v * pscale);
                } else {
                    ((float*)Cv)[idx] = v + bias[m] + resid[(size_t)bz * sRb + (size_t)m * N + n];
                }
            }
            if constexpr (EPI == 2) {
                // reduce over the 16 lc lanes (64 cols of this wave)
                rsacc += __shfl_xor(rsacc, 1);
                rsacc += __shfl_xor(rsacc, 2);
                rsacc += __shfl_xor(rsacc, 4);
                rsacc += __shfl_xor(rsacc, 8);
                if (lc == 0) atomicAdd(&rowsum[(size_t)bz * M + m], rsacc);
            }
        }
    }
}

extern "C" void kernel_launch(void* const* d_in, const int* in_sizes, int n_in,
                              void* d_out, int out_size, void* d_ws, size_t ws_size,
                              hipStream_t stream) {
    (void)in_sizes; (void)n_in; (void)out_size; (void)ws_size;
    const float* x   = (const float*)d_in[0];
    const float* gnw = (const float*)d_in[1];
    const float* gnb = (const float*)d_in[2];
    const float* qw  = (const float*)d_in[3];
    const float* qb  = (const float*)d_in[4];
    const float* kw  = (const float*)d_in[5];
    const float* kb  = (const float*)d_in[6];
    const float* vw  = (const float*)d_in[7];
    const float* vb  = (const float*)d_in[8];
    const float* pw  = (const float*)d_in[9];
    const float* pb  = (const float*)d_in[10];
    float* out = (float*)d_out;

    char* ws = (char*)d_ws;
    // layout (bytes): h_t 0..16M (reused as O_t), q_t 16M, k_t 32M, v 48M,
    // weights 64M..66M, stats+rowsum 66M, scores 67M..195M
    unsigned short* h_t = (unsigned short*)(ws);
    unsigned short* o_t = h_t;  // alias: h_t dead after v GEMM
    unsigned short* q_t = (unsigned short*)(ws + (16ull << 20));
    unsigned short* k_t = (unsigned short*)(ws + (32ull << 20));
    unsigned short* vv  = (unsigned short*)(ws + (48ull << 20));
    unsigned short* wqb = (unsigned short*)(ws + (64ull << 20));
    unsigned short* wkb = wqb + 262144;
    unsigned short* wvb = wqb + 2 * 262144;
    unsigned short* wpb = wqb + 3 * 262144;
    float* stats  = (float*)(ws + (66ull << 20));
    float* rowsum = (float*)(ws + (66ull << 20) + 65536);  // 4*4096 floats
    unsigned short* sc = (unsigned short*)(ws + (67ull << 20));

    const long long sP = 2097152;   // 4096*512 elements per batch
    const long long sS = 16777216;  // 4096*4096 elements per batch

    cvt_bf16_kernel<<<256, 256, 0, stream>>>(qw, wqb, 65536);
    cvt_bf16_kernel<<<256, 256, 0, stream>>>(kw, wkb, 65536);
    cvt_bf16_kernel<<<256, 256, 0, stream>>>(vw, wvb, 65536);
    cvt_bf16_kernel<<<256, 256, 0, stream>>>(pw, wpb, 65536);
    gn_stats_kernel<<<128, 256, 0, stream>>>(x, stats, rowsum);
    gn_apply_kernel<<<dim3(64, 8, 4), 256, 0, stream>>>(x, stats, gnw, gnb, h_t);
    // q_t[p][o], k_t[p][o]: M=4096(p), N=512(o), K=512(c)
    gemm_nt<0, false><<<dim3(4, 32, 4), 256, 0, stream>>>(h_t, sP, wqb, 0, q_t, sP, qb, nullptr, 0,
                                                          nullptr, 4096, 512, 512, 1.f);
    gemm_nt<0, false><<<dim3(4, 32, 4), 256, 0, stream>>>(h_t, sP, wkb, 0, k_t, sP, kb, nullptr, 0,
                                                          nullptr, 4096, 512, 512, 1.f);
    // v[d][p]: M=512(d), N=4096(p), K=512(c)
    gemm_nt<1, false><<<dim3(32, 4, 4), 256, 0, stream>>>(wvb, 0, h_t, sP, vv, sP, vb, nullptr, 0,
                                                          nullptr, 512, 4096, 512, 1.f);
    // S[q][k] = exp(q_t . k_t^T * C^-0.5), rowsum accumulated : M=N=4096, K=512
    gemm_nt<2, false><<<dim3(32, 32, 4), 256, 0, stream>>>(q_t, sP, k_t, sP, sc, sS, nullptr, nullptr, 0,
                                                           rowsum, 4096, 4096, 512, 0.044194173824159216f);
    // O_t[q][d] = (S . v^T) / rowsum[q]: M=4096(q), N=512(d), K=4096(k), XCD-swizzled
    gemm_nt<3, true><<<dim3(512, 1, 1), 256, 0, stream>>>(sc, sS, vv, sP, o_t, sP, rowsum, nullptr, 0,
                                                          nullptr, 4096, 512, 4096, 1.f);
    // y[o][p] = x + pw . O_t^T + pb : M=512(o), N=4096(p), K=512(d)
    gemm_nt<4, false><<<dim3(32, 4, 4), 256, 0, stream>>>(wpb, 0, o_t, sP, (void*)out, sP, pb, x, sP,
                                                          nullptr, 512, 4096, 512, 1.f);
}